// Round 2
// baseline (1768.505 us; speedup 1.0000x reference)
//
#include <hip/hip_runtime.h>
#include <hip/hip_bf16.h>

// HeteroGCN: 2-layer, 3-relation GraphConv (norm='both') on MI355X.
// Pipeline:
//   1. degree count (atomic u32)                 -> deg_out, deg_in per relation
//   2. prep: rsqrt degrees + CSR range assignment (wave-scan + 1 atomic/wave)
//   3. CSR fill: slot = atomicAdd(cursor[dst]); csr_src[slot] = src
//   4. per relation r: GEMM1 (x @ W1[r]) * rs_out  -> feat   (row-scale commutes)
//                      AGG1 gather-sum via CSR, * rs_in, (+bias,ReLU on last r) -> h1
//   5. GEMM2 (wave-per-node, 6 outputs) * rs_out -> feat2[3][N][2]
//   6. AGG2 gather-sum + bias -> out[N][2]

#define N_REL 3
#define IN_F 256
#define HID_F 128

// ---------------- degree count ----------------
__global__ void HeteroGCN_degree_kernel(const int* __restrict__ edges,
                                        unsigned* __restrict__ deg_out,
                                        unsigned* __restrict__ deg_in,
                                        int N, int E) {
  int e = blockIdx.x * blockDim.x + threadIdx.x;
  int r = blockIdx.y;
  if (e >= E) return;
  const int* ep = edges + (size_t)r * 2 * E;
  int src = ep[e];
  int dst = ep[E + e];
  atomicAdd(&deg_out[r * N + src], 1u);
  atomicAdd(&deg_in[r * N + dst], 1u);
}

// ---------------- prep: rsqrt + CSR offsets (wave-scan) ----------------
__global__ void HeteroGCN_prep_kernel(const unsigned* __restrict__ deg_out,
                                      const unsigned* __restrict__ deg_in,
                                      float* __restrict__ rs_out,
                                      float* __restrict__ rs_in,
                                      int* __restrict__ offsets,
                                      int* __restrict__ cursor,
                                      unsigned* __restrict__ counters, int N) {
  int n = blockIdx.x * blockDim.x + threadIdx.x;
  int r = blockIdx.y;
  int lane = threadIdx.x & 63;
  bool valid = n < N;
  unsigned dco = 0, dci = 0;
  if (valid) {
    dco = deg_out[r * N + n];
    dci = deg_in[r * N + n];
  }
  // inclusive wave scan of dci
  unsigned pre = dci;
  #pragma unroll
  for (int d = 1; d < 64; d <<= 1) {
    unsigned t = __shfl_up(pre, (unsigned)d, 64);
    if (lane >= d) pre += t;
  }
  unsigned base = 0;
  if (lane == 63) base = atomicAdd(&counters[r], pre);  // pre @63 = wave total
  base = __shfl(base, 63, 64);
  if (valid) {
    rs_out[r * N + n] = rsqrtf((float)max(dco, 1u));
    rs_in[r * N + n] = rsqrtf((float)max(dci, 1u));
    int off = (int)(base + pre - dci);  // exclusive
    offsets[r * N + n] = off;
    cursor[r * N + n] = off;
  }
}

// ---------------- CSR fill ----------------
__global__ void HeteroGCN_csrfill_kernel(const int* __restrict__ edges,
                                         int* __restrict__ cursor,
                                         int* __restrict__ csr_src, int N, int E) {
  int e = blockIdx.x * blockDim.x + threadIdx.x;
  int r = blockIdx.y;
  if (e >= E) return;
  const int* ep = edges + (size_t)r * 2 * E;
  int src = ep[e];
  int dst = ep[E + e];
  int slot = atomicAdd(&cursor[r * N + dst], 1);
  csr_src[(size_t)r * E + slot] = src;
}

// ---------------- GEMM1: feat = (x @ W) * rs_out, M x 256 @ 256 x 128 ----------
// BM=64, BN=128, BK=64. 256 threads; thread computes 4 rows x 8 cols.
__global__ __launch_bounds__(256) void HeteroGCN_gemm1_kernel(
    const float* __restrict__ x, const float* __restrict__ W,
    const float* __restrict__ rs_out, float* __restrict__ feat, int M) {
  __shared__ float As[64][68];   // pad 68: 4-row-apart broadcast reads land 2 banks
  __shared__ float Bs[64][128];
  int tid = threadIdx.x;
  int block_row = blockIdx.x * 64;
  int rg = tid >> 4;          // 0..15
  int cg = tid & 15;          // 0..15
  int row0 = rg * 4;
  int colA = cg * 4;          // cols [colA, colA+3] and [64+colA, 64+colA+3]
  float acc[4][8] = {};
  for (int k0 = 0; k0 < IN_F; k0 += 64) {
    #pragma unroll
    for (int i = 0; i < 4; ++i) {   // As: 64x64 floats = 1024 float4
      int f4 = tid + i * 256;
      int rr = f4 >> 4;
      int cc = (f4 & 15) << 2;
      int grow = block_row + rr;
      float4 v = make_float4(0.f, 0.f, 0.f, 0.f);
      if (grow < M) v = *(const float4*)(x + (size_t)grow * IN_F + k0 + cc);
      *(float4*)(&As[rr][cc]) = v;
    }
    #pragma unroll
    for (int i = 0; i < 8; ++i) {   // Bs: 64x128 floats = 2048 float4
      int f4 = tid + i * 256;
      int rr = f4 >> 5;
      int cc = (f4 & 31) << 2;
      *(float4*)(&Bs[rr][cc]) = *(const float4*)(W + (size_t)(k0 + rr) * HID_F + cc);
    }
    __syncthreads();
    #pragma unroll
    for (int kk = 0; kk < 64; ++kk) {
      float a[4];
      #pragma unroll
      for (int i = 0; i < 4; ++i) a[i] = As[row0 + i][kk];
      float4 b0 = *(const float4*)(&Bs[kk][colA]);
      float4 b1 = *(const float4*)(&Bs[kk][64 + colA]);
      #pragma unroll
      for (int i = 0; i < 4; ++i) {
        acc[i][0] += a[i] * b0.x; acc[i][1] += a[i] * b0.y;
        acc[i][2] += a[i] * b0.z; acc[i][3] += a[i] * b0.w;
        acc[i][4] += a[i] * b1.x; acc[i][5] += a[i] * b1.y;
        acc[i][6] += a[i] * b1.z; acc[i][7] += a[i] * b1.w;
      }
    }
    __syncthreads();
  }
  #pragma unroll
  for (int i = 0; i < 4; ++i) {
    int grow = block_row + row0 + i;
    if (grow < M) {
      float s = rs_out[grow];
      float4 v0 = make_float4(acc[i][0] * s, acc[i][1] * s, acc[i][2] * s, acc[i][3] * s);
      float4 v1 = make_float4(acc[i][4] * s, acc[i][5] * s, acc[i][6] * s, acc[i][7] * s);
      *(float4*)(feat + (size_t)grow * HID_F + colA) = v0;
      *(float4*)(feat + (size_t)grow * HID_F + 64 + colA) = v1;
    }
  }
}

// ---------------- AGG1: h1 accumulation via CSR gather ----------------
// 256 threads = 2 nodes x 128 feats. rel==2 adds bias-sum and applies ReLU.
// 4-way ILP on the gather: 4 independent loads in flight per thread
// (latency-bound kernel; feat is L3-resident so BW is not the limit).
__global__ __launch_bounds__(256) void HeteroGCN_agg1_kernel(
    const float* __restrict__ feat, const int* __restrict__ csr_r,
    const int* __restrict__ offsets_r, const unsigned* __restrict__ deg_in_r,
    const float* __restrict__ rs_in_r, const float* __restrict__ b1,
    float* __restrict__ h1, int N, int rel) {
  int half = threadIdx.x >> 7;
  int f = threadIdx.x & 127;
  int n = blockIdx.x * 2 + half;
  if (n >= N) return;
  int off = offsets_r[n];
  int cnt = (int)deg_in_r[n];
  const int* sp = csr_r + off;
  float a0 = 0.f, a1 = 0.f, a2 = 0.f, a3 = 0.f;
  int i = 0;
  for (; i + 3 < cnt; i += 4) {
    int s0 = sp[i], s1 = sp[i + 1], s2 = sp[i + 2], s3 = sp[i + 3];
    a0 += feat[(size_t)s0 * HID_F + f];
    a1 += feat[(size_t)s1 * HID_F + f];
    a2 += feat[(size_t)s2 * HID_F + f];
    a3 += feat[(size_t)s3 * HID_F + f];
  }
  for (; i < cnt; ++i) a0 += feat[(size_t)sp[i] * HID_F + f];
  float v = ((a0 + a1) + (a2 + a3)) * rs_in_r[n];
  size_t oi = (size_t)n * HID_F + f;
  if (rel == 0) {
    h1[oi] = v;
  } else if (rel == 1) {
    h1[oi] += v;
  } else {
    float b = b1[f] + b1[HID_F + f] + b1[2 * HID_F + f];
    h1[oi] = fmaxf(h1[oi] + v + b, 0.f);
  }
}

// ---------------- GEMM2: feat2[r][n][c] = (h1[n] . W2[r][:,c]) * rs_out[r][n] ----
// one wave per node; 64 lanes x 2 k-elems; 6 outputs reduced via shfl_xor.
__global__ __launch_bounds__(256) void HeteroGCN_gemm2_kernel(
    const float* __restrict__ h1, const float* __restrict__ W2,
    const float* __restrict__ rs_out, float* __restrict__ feat2, int N) {
  int wid = (blockIdx.x * blockDim.x + threadIdx.x) >> 6;
  int lane = threadIdx.x & 63;
  if (wid >= N) return;
  float2 h = *(const float2*)(h1 + (size_t)wid * HID_F + lane * 2);
  float p[6];
  #pragma unroll
  for (int r = 0; r < 3; ++r) {
    #pragma unroll
    for (int c = 0; c < 2; ++c) {
      float w0 = W2[((size_t)r * HID_F + lane * 2) * 2 + c];
      float w1 = W2[((size_t)r * HID_F + lane * 2 + 1) * 2 + c];
      p[r * 2 + c] = h.x * w0 + h.y * w1;
    }
  }
  #pragma unroll
  for (int o = 32; o > 0; o >>= 1) {
    #pragma unroll
    for (int q = 0; q < 6; ++q) p[q] += __shfl_xor(p[q], o, 64);
  }
  if (lane == 0) {
    #pragma unroll
    for (int q = 0; q < 6; ++q) {
      int r = q >> 1, c = q & 1;
      feat2[((size_t)r * N + wid) * 2 + c] = p[q] * rs_out[r * N + wid];
    }
  }
}

// ---------------- AGG2: out[n][c] = sum_r rs_in * sum_src feat2 + bias ---------
// 3 relations kept as independent accumulator chains + 2-way unroll -> >=6
// loads in flight per thread. feat2 (2.4 MB) is L2-resident.
__global__ __launch_bounds__(256) void HeteroGCN_agg2_kernel(
    const float* __restrict__ feat2, const int* __restrict__ csr_src,
    const int* __restrict__ offsets, const unsigned* __restrict__ deg_in,
    const float* __restrict__ rs_in, const float* __restrict__ b2,
    float* __restrict__ out, int N, int E) {
  int n = blockIdx.x * blockDim.x + threadIdx.x;
  if (n >= N) return;
  float o0 = 0.f, o1 = 0.f;
  #pragma unroll
  for (int r = 0; r < 3; ++r) {
    int off = offsets[r * N + n];
    int cnt = (int)deg_in[r * N + n];
    const int* sp = csr_src + (size_t)r * E + off;
    const float* fp = feat2 + (size_t)r * N * 2;
    float a0 = 0.f, a1 = 0.f, c0 = 0.f, c1 = 0.f;
    int i = 0;
    for (; i + 1 < cnt; i += 2) {
      int s0 = sp[i], s1 = sp[i + 1];
      float2 f0 = *(const float2*)(fp + (size_t)s0 * 2);
      float2 f1 = *(const float2*)(fp + (size_t)s1 * 2);
      a0 += f0.x; a1 += f0.y;
      c0 += f1.x; c1 += f1.y;
    }
    if (i < cnt) {
      float2 f0 = *(const float2*)(fp + (size_t)sp[i] * 2);
      a0 += f0.x; a1 += f0.y;
    }
    float ri = rs_in[r * N + n];
    o0 += (a0 + c0) * ri + b2[r * 2 + 0];
    o1 += (a1 + c1) * ri + b2[r * 2 + 1];
  }
  *(float2*)(out + (size_t)n * 2) = make_float2(o0, o1);
}

extern "C" void kernel_launch(void* const* d_in, const int* in_sizes, int n_in,
                              void* d_out, int out_size, void* d_ws, size_t ws_size,
                              hipStream_t stream) {
  const float* x = (const float*)d_in[0];
  const int* edges = (const int*)d_in[1];
  const float* W1 = (const float*)d_in[2];
  const float* b1 = (const float*)d_in[3];
  const float* W2 = (const float*)d_in[4];
  const float* b2 = (const float*)d_in[5];
  float* out = (float*)d_out;

  const int N = in_sizes[0] / IN_F;          // 100000
  const int E = in_sizes[1] / (N_REL * 2);   // 1600000

  // workspace layout (256B aligned)
  char* ws = (char*)d_ws;
  size_t p = 0;
  auto take = [&](size_t b) { size_t o = p; p += (b + 255) & ~(size_t)255; return o; };
  size_t deg_out_off = take((size_t)N_REL * N * 4);
  size_t deg_in_off  = take((size_t)N_REL * N * 4);
  size_t counters_off = take(256);
  size_t rs_out_off  = take((size_t)N_REL * N * 4);
  size_t rs_in_off   = take((size_t)N_REL * N * 4);
  size_t offsets_off = take((size_t)N_REL * N * 4);
  size_t cursor_off  = take((size_t)N_REL * N * 4);
  size_t csr_off     = take((size_t)N_REL * E * 4);
  size_t feat_off    = take((size_t)N * HID_F * 4);
  size_t h1_off      = take((size_t)N * HID_F * 4);
  size_t feat2_off   = take((size_t)N_REL * N * 2 * 4);
  (void)ws_size;

  unsigned* deg_out = (unsigned*)(ws + deg_out_off);
  unsigned* deg_in  = (unsigned*)(ws + deg_in_off);
  unsigned* counters = (unsigned*)(ws + counters_off);
  float* rs_out = (float*)(ws + rs_out_off);
  float* rs_in  = (float*)(ws + rs_in_off);
  int* offsets = (int*)(ws + offsets_off);
  int* cursor  = (int*)(ws + cursor_off);
  int* csr_src = (int*)(ws + csr_off);
  float* feat  = (float*)(ws + feat_off);
  float* h1    = (float*)(ws + h1_off);
  float* feat2 = (float*)(ws + feat2_off);

  // zero the atomic count region (deg_out | deg_in | counters are contiguous)
  hipMemsetAsync(ws + deg_out_off, 0, counters_off + 256 - deg_out_off, stream);

  dim3 blk(256);
  dim3 grdE((E + 255) / 256, N_REL);
  HeteroGCN_degree_kernel<<<grdE, blk, 0, stream>>>(edges, deg_out, deg_in, N, E);

  dim3 grdN((N + 255) / 256, N_REL);
  HeteroGCN_prep_kernel<<<grdN, blk, 0, stream>>>(deg_out, deg_in, rs_out, rs_in,
                                                  offsets, cursor, counters, N);

  HeteroGCN_csrfill_kernel<<<grdE, blk, 0, stream>>>(edges, cursor, csr_src, N, E);

  // layer 1, relation by relation (feat buffer reused)
  for (int r = 0; r < N_REL; ++r) {
    HeteroGCN_gemm1_kernel<<<dim3((N + 63) / 64), blk, 0, stream>>>(
        x, W1 + (size_t)r * IN_F * HID_F, rs_out + (size_t)r * N, feat, N);
    HeteroGCN_agg1_kernel<<<dim3((N + 1) / 2), blk, 0, stream>>>(
        feat, csr_src + (size_t)r * E, offsets + (size_t)r * N,
        deg_in + (size_t)r * N, rs_in + (size_t)r * N, b1, h1, N, r);
  }

  // layer 2
  HeteroGCN_gemm2_kernel<<<dim3((N * 64 + 255) / 256), blk, 0, stream>>>(
      h1, W2, rs_out, feat2, N);
  HeteroGCN_agg2_kernel<<<dim3((N + 255) / 256), blk, 0, stream>>>(
      feat2, csr_src, offsets, deg_in, rs_in, b2, out, N, E);
}